// Round 1
// baseline (884.997 us; speedup 1.0000x reference)
//
#include <hip/hip_runtime.h>
#include <math.h>

#define DIM   1024
#define NTOK  4096
#define TSEQ  1024
#define NHEAD 16
#define MPROT 256
#define EPSR  1.1920929e-07f
#define SA    64.0f
#define SW    256.0f
#define SPC   64.0f

typedef __attribute__((ext_vector_type(8))) short          short8;
typedef __attribute__((ext_vector_type(8))) _Float16       half8;
typedef __attribute__((ext_vector_type(4))) _Float16       half4;
typedef __attribute__((ext_vector_type(4))) float          f32x4;
typedef __attribute__((ext_vector_type(4))) unsigned short us4;

static __device__ __forceinline__ float bf2f(unsigned short s) {
  union { unsigned int u; float f; } c; c.u = ((unsigned int)s) << 16; return c.f;
}
static __device__ __forceinline__ unsigned short f2bf(float f) {
  union { float f; unsigned int u; } c; c.f = f;
  return (unsigned short)((c.u + 0x7fffu + ((c.u >> 16) & 1u)) >> 16);
}
static __device__ __forceinline__ void gload16(void* lds, const void* g) {
  __builtin_amdgcn_global_load_lds(
      (__attribute__((address_space(1))) void*)const_cast<void*>(g),
      (__attribute__((address_space(3))) void*)lds, 16, 0, 0);
}

// ---------------- conversions ----------------
__global__ __launch_bounds__(256) void cvt_split_k(const float* __restrict__ s,
                                                   _Float16* __restrict__ hi,
                                                   _Float16* __restrict__ lo,
                                                   int n4, float scale) {
  int i = blockIdx.x * 256 + threadIdx.x;
  const int st = gridDim.x * 256;
  for (; i < n4; i += st) {
    const float4 v = ((const float4*)s)[i];
    float a0 = v.x * scale, a1 = v.y * scale, a2 = v.z * scale, a3 = v.w * scale;
    half4 hv, lv;
    _Float16 h0 = (_Float16)a0; hv[0] = h0; lv[0] = (_Float16)(a0 - (float)h0);
    _Float16 h1 = (_Float16)a1; hv[1] = h1; lv[1] = (_Float16)(a1 - (float)h1);
    _Float16 h2 = (_Float16)a2; hv[2] = h2; lv[2] = (_Float16)(a2 - (float)h2);
    _Float16 h3 = (_Float16)a3; hv[3] = h3; lv[3] = (_Float16)(a3 - (float)h3);
    ((half4*)hi)[i] = hv; ((half4*)lo)[i] = lv;
  }
}

__global__ __launch_bounds__(256) void cvt_bf16_k(const float* __restrict__ s,
                                                  unsigned short* __restrict__ d, int n4) {
  int i = blockIdx.x * 256 + threadIdx.x;
  const int st = gridDim.x * 256;
  for (; i < n4; i += st) {
    const float4 v = ((const float4*)s)[i];
    us4 o; o[0] = f2bf(v.x); o[1] = f2bf(v.y); o[2] = f2bf(v.z); o[3] = f2bf(v.w);
    ((us4*)d)[i] = o;
  }
}

// ---------------- RMS norms ----------------
__global__ __launch_bounds__(256) void rms_split_k(const float* __restrict__ in,
                                                   const float* __restrict__ wgt,
                                                   _Float16* __restrict__ oh,
                                                   _Float16* __restrict__ ol) {
  const int row = blockIdx.x, tid = threadIdx.x;
  const float4 v = ((const float4*)(in + (size_t)row * DIM))[tid];
  float ss = v.x * v.x + v.y * v.y + v.z * v.z + v.w * v.w;
#pragma unroll
  for (int o = 32; o; o >>= 1) ss += __shfl_xor(ss, o);
  __shared__ float red[4];
  if ((tid & 63) == 0) red[tid >> 6] = ss;
  __syncthreads();
  const float sc = rsqrtf((red[0] + red[1] + red[2] + red[3]) * (1.0f / DIM) + EPSR) * SA;
  const float4 wv = ((const float4*)wgt)[tid];
  float a[4] = {v.x * sc * wv.x, v.y * sc * wv.y, v.z * sc * wv.z, v.w * sc * wv.w};
  half4 hv, lv;
#pragma unroll
  for (int j = 0; j < 4; ++j) {
    _Float16 hh = (_Float16)a[j]; hv[j] = hh; lv[j] = (_Float16)(a[j] - (float)hh);
  }
  ((half4*)(oh + (size_t)row * DIM))[tid] = hv;
  ((half4*)(ol + (size_t)row * DIM))[tid] = lv;
}

__global__ __launch_bounds__(256) void rms_bf16_k(const float* __restrict__ in,
                                                  const float* __restrict__ wgt,
                                                  unsigned short* __restrict__ outp) {
  const int row = blockIdx.x, tid = threadIdx.x;
  const float4 v = ((const float4*)(in + (size_t)row * DIM))[tid];
  float ss = v.x * v.x + v.y * v.y + v.z * v.z + v.w * v.w;
#pragma unroll
  for (int o = 32; o; o >>= 1) ss += __shfl_xor(ss, o);
  __shared__ float red[4];
  if ((tid & 63) == 0) red[tid >> 6] = ss;
  __syncthreads();
  const float sc = rsqrtf((red[0] + red[1] + red[2] + red[3]) * (1.0f / DIM) + EPSR);
  const float4 wv = ((const float4*)wgt)[tid];
  us4 o;
  o[0] = f2bf(v.x * sc * wv.x); o[1] = f2bf(v.y * sc * wv.y);
  o[2] = f2bf(v.z * sc * wv.z); o[3] = f2bf(v.w * sc * wv.w);
  ((us4*)(outp + (size_t)row * DIM))[tid] = o;
}

// per (token,head) RMS over 64 dims, in place on split planes (values carry ×SA)
__global__ __launch_bounds__(256) void qknorm_k(_Float16* __restrict__ qh,
                                                _Float16* __restrict__ ql,
                                                const float* __restrict__ wgt) {
  const int idx = (blockIdx.x << 2) + (threadIdx.x >> 6);
  const int lane = threadIdx.x & 63;
  const size_t off = ((size_t)idx << 6) + lane;
  const float v = (float)qh[off] + (float)ql[off];
  float ss = v * v;
#pragma unroll
  for (int o = 32; o; o >>= 1) ss += __shfl_xor(ss, o);
  const float sc = rsqrtf(ss * (1.0f / (64.0f * SA * SA)) + EPSR);
  const float nv = v * sc * wgt[lane];
  _Float16 hh = (_Float16)nv;
  qh[off] = hh; ql[off] = (_Float16)(nv - (float)hh);
}

// ---------------- gate: fp32 logits from fp32 x2, softmax, top-2 ----------------
__global__ __launch_bounds__(256) void gate_k(const float* __restrict__ x2,
                                              const float* __restrict__ n2w,
                                              const float* __restrict__ gw,
                                              float* __restrict__ wts) {
  const int row = blockIdx.x, tid = threadIdx.x;
  const float4 v = ((const float4*)(x2 + (size_t)row * DIM))[tid];
  float ss = v.x * v.x + v.y * v.y + v.z * v.z + v.w * v.w;
#pragma unroll
  for (int o = 32; o; o >>= 1) ss += __shfl_xor(ss, o);
  __shared__ float red[4];
  __shared__ float redE[4][4];
  const int w = tid >> 6, lane = tid & 63;
  if (lane == 0) red[w] = ss;
  __syncthreads();
  const float sc = rsqrtf((red[0] + red[1] + red[2] + red[3]) * (1.0f / DIM) + EPSR);
  const float4 nw = ((const float4*)n2w)[tid];
  const float xn0 = v.x * sc * nw.x, xn1 = v.y * sc * nw.y;
  const float xn2 = v.z * sc * nw.z, xn3 = v.w * sc * nw.w;
#pragma unroll
  for (int e = 0; e < 4; ++e) {
    const float4 g = ((const float4*)(gw + (size_t)e * DIM))[tid];
    float d = xn0 * g.x + xn1 * g.y + xn2 * g.z + xn3 * g.w;
#pragma unroll
    for (int o = 32; o; o >>= 1) d += __shfl_xor(d, o);
    if (lane == 0) redE[w][e] = d;
  }
  __syncthreads();
  if (tid == 0) {
    float lg[4];
#pragma unroll
    for (int e = 0; e < 4; ++e) lg[e] = redE[0][e] + redE[1][e] + redE[2][e] + redE[3][e];
    const float mx = fmaxf(fmaxf(lg[0], lg[1]), fmaxf(lg[2], lg[3]));
    float pe[4]; float sum = 0.0f;
#pragma unroll
    for (int e = 0; e < 4; ++e) { pe[e] = __expf(lg[e] - mx); sum += pe[e]; }
#pragma unroll
    for (int e = 0; e < 4; ++e) pe[e] /= sum;
    int i1 = 0;
    for (int e = 1; e < 4; ++e) if (pe[e] > pe[i1]) i1 = e;
    int i2 = -1;
    for (int e = 0; e < 4; ++e) { if (e == i1) continue; if (i2 < 0 || pe[e] > pe[i2]) i2 = e; }
    const float s2 = pe[i1] + pe[i2] + 1e-8f;
    float o[4] = {0.f, 0.f, 0.f, 0.f};
    o[i1] = pe[i1] / s2; o[i2] = pe[i2] / s2;
    float4 r; r.x = o[0]; r.y = o[1]; r.z = o[2]; r.w = o[3];
    *(float4*)(wts + (size_t)row * 4) = r;
  }
}

// ---------------- bf16 GEMM: out = epilogue(A[M,K] @ W[F,K]^T) ----------------
// ACT: 0=none 1=gelu ; EP: 0=store bf16, 1=silu(v)*other->bf16, 2=moe first(=), 3=moe acc(+=)
template <int ACT, int EP>
__global__ __launch_bounds__(256, 2) void gemm_bf16_k(
    const unsigned short* __restrict__ A, const unsigned short* __restrict__ Bw,
    int K, int F,
    unsigned short* __restrict__ outb, const unsigned short* __restrict__ other,
    float* __restrict__ outf, const float* __restrict__ wts, int expert) {
  __shared__ unsigned short As[2][128][64];
  __shared__ unsigned short Bs[2][128][64];
  const int tid = threadIdx.x;
  const int w = tid >> 6, lane = tid & 63;
  const int wr = ((w >> 1) << 6), wc = ((w & 1) << 6);
  const int m0 = blockIdx.y << 7, n0 = blockIdx.x << 7;
  const int rr = lane & 15, kgl = lane >> 4;
  const int srow = tid >> 3, sslot = tid & 7;

  f32x4 acc[4][4];
#pragma unroll
  for (int a_ = 0; a_ < 4; ++a_)
#pragma unroll
    for (int b_ = 0; b_ < 4; ++b_) acc[a_][b_] = (f32x4){0.f, 0.f, 0.f, 0.f};

  const int KT = K >> 6;
  auto stage = [&](int buf, int kt) {
    const int k0 = kt << 6;
#pragma unroll
    for (int i = 0; i < 4; ++i) {
      const int r = (i << 5) + srow;
      const int ls = sslot ^ (r & 7);
      gload16(&As[buf][(i << 5) + (w << 3)][0], A + (size_t)(m0 + r) * K + k0 + (ls << 3));
      gload16(&Bs[buf][(i << 5) + (w << 3)][0], Bw + (size_t)(n0 + r) * K + k0 + (ls << 3));
    }
  };
  stage(0, 0);
  __syncthreads();
  for (int kt = 0; kt < KT; ++kt) {
    const int cur = kt & 1;
    if (kt + 1 < KT) stage(cur ^ 1, kt + 1);
    short8 af[4][2], bfr[4][2];
#pragma unroll
    for (int f = 0; f < 4; ++f) {
#pragma unroll
      for (int ks = 0; ks < 2; ++ks) {
        const int row = wr + (f << 4) + rr;
        const int kg = (ks << 2) + kgl;
        af[f][ks] = *(const short8*)&As[cur][row][(kg ^ (row & 7)) << 3];
        const int col = wc + (f << 4) + rr;
        bfr[f][ks] = *(const short8*)&Bs[cur][col][(kg ^ (col & 7)) << 3];
      }
    }
#pragma unroll
    for (int fi = 0; fi < 4; ++fi)
#pragma unroll
      for (int fj = 0; fj < 4; ++fj)
#pragma unroll
        for (int ks = 0; ks < 2; ++ks)
          acc[fi][fj] = __builtin_amdgcn_mfma_f32_16x16x32_bf16(
              af[fi][ks], bfr[fj][ks], acc[fi][fj], 0, 0, 0);
    __syncthreads();
  }
#pragma unroll
  for (int fi = 0; fi < 4; ++fi)
#pragma unroll
    for (int fj = 0; fj < 4; ++fj) {
      const int col = n0 + wc + (fj << 4) + rr;
#pragma unroll
      for (int r = 0; r < 4; ++r) {
        const int row = m0 + wr + (fi << 4) + (kgl << 2) + r;
        float v = acc[fi][fj][r];
        if (ACT == 1) v = 0.5f * v * (1.0f + erff(v * 0.70710678118654752f));
        const size_t off = (size_t)row * F + col;
        if (EP == 0) {
          outb[off] = f2bf(v);
        } else if (EP == 1) {
          const float sv = v / (1.0f + __expf(-v));
          outb[off] = f2bf(sv * bf2f(other[off]));
        } else if (EP == 2) {
          outf[off] = wts[(size_t)row * 4 + expert] * v;
        } else {
          outf[off] += wts[(size_t)row * 4 + expert] * v;
        }
      }
    }
}

// ---------------- fp16x2 split GEMM (3-term) ----------------
// EP: 0 = write split pair (value*oscale), 1 = fp32: resid + masked(value*oscale)
template <int EP>
__global__ __launch_bounds__(256, 2) void gemm_split_k(
    const _Float16* __restrict__ Ah, const _Float16* __restrict__ Al,
    const _Float16* __restrict__ Bh, const _Float16* __restrict__ Bl,
    int K, int F,
    _Float16* __restrict__ Oh, _Float16* __restrict__ Ol, float oscale,
    const float* __restrict__ resid, float* __restrict__ outf) {
  __shared__ _Float16 AsH[2][128][32], AsL[2][128][32];
  __shared__ _Float16 BsH[2][128][32], BsL[2][128][32];
  const int tid = threadIdx.x;
  const int w = tid >> 6, lane = tid & 63;
  const int wr = ((w >> 1) << 6), wc = ((w & 1) << 6);
  const int m0 = blockIdx.y << 7, n0 = blockIdx.x << 7;
  const int rr = lane & 15, kgl = lane >> 4;
  const int srow = tid >> 2, sslot = tid & 3;

  f32x4 acc[4][4];
#pragma unroll
  for (int a_ = 0; a_ < 4; ++a_)
#pragma unroll
    for (int b_ = 0; b_ < 4; ++b_) acc[a_][b_] = (f32x4){0.f, 0.f, 0.f, 0.f};

  const int KT = K >> 5;
  auto stage = [&](int buf, int kt) {
    const int k0 = kt << 5;
#pragma unroll
    for (int i = 0; i < 2; ++i) {
      const int r = (i << 6) + srow;
      const int ls = sslot ^ ((r >> 1) & 3);
      const size_t ga = (size_t)(m0 + r) * K + k0 + (ls << 3);
      const size_t gb = (size_t)(n0 + r) * K + k0 + (ls << 3);
      const int lr = (i << 6) + (w << 4);
      gload16(&AsH[buf][lr][0], Ah + ga);
      gload16(&AsL[buf][lr][0], Al + ga);
      gload16(&BsH[buf][lr][0], Bh + gb);
      gload16(&BsL[buf][lr][0], Bl + gb);
    }
  };
  stage(0, 0);
  __syncthreads();
  for (int kt = 0; kt < KT; ++kt) {
    const int cur = kt & 1;
    if (kt + 1 < KT) stage(cur ^ 1, kt + 1);
    half8 ah[4], al[4], bh[4], bl[4];
#pragma unroll
    for (int f = 0; f < 4; ++f) {
      const int row = wr + (f << 4) + rr;
      const int pa = (kgl ^ ((row >> 1) & 3)) << 3;
      ah[f] = *(const half8*)&AsH[cur][row][pa];
      al[f] = *(const half8*)&AsL[cur][row][pa];
      const int col = wc + (f << 4) + rr;
      const int pb = (kgl ^ ((col >> 1) & 3)) << 3;
      bh[f] = *(const half8*)&BsH[cur][col][pb];
      bl[f] = *(const half8*)&BsL[cur][col][pb];
    }
#pragma unroll
    for (int fi = 0; fi < 4; ++fi)
#pragma unroll
      for (int fj = 0; fj < 4; ++fj) {
        acc[fi][fj] = __builtin_amdgcn_mfma_f32_16x16x32_f16(ah[fi], bh[fj], acc[fi][fj], 0, 0, 0);
        acc[fi][fj] = __builtin_amdgcn_mfma_f32_16x16x32_f16(ah[fi], bl[fj], acc[fi][fj], 0, 0, 0);
        acc[fi][fj] = __builtin_amdgcn_mfma_f32_16x16x32_f16(al[fi], bh[fj], acc[fi][fj], 0, 0, 0);
      }
    __syncthreads();
  }
#pragma unroll
  for (int fi = 0; fi < 4; ++fi)
#pragma unroll
    for (int fj = 0; fj < 4; ++fj) {
      const int col = n0 + wc + (fj << 4) + rr;
#pragma unroll
      for (int r = 0; r < 4; ++r) {
        const int row = m0 + wr + (fi << 4) + (kgl << 2) + r;
        const size_t off = (size_t)row * F + col;
        const float v = acc[fi][fj][r] * oscale;
        if (EP == 0) {
          const _Float16 hh = (_Float16)v;
          Oh[off] = hh; Ol[off] = (_Float16)(v - (float)hh);
        } else {
          outf[off] = resid[off] + (col >= MPROT ? v : 0.0f);
        }
      }
    }
}

// ---------------- flash attention, causal, fp16x2 split ----------------
__global__ __launch_bounds__(256, 2) void attn_k(
    const _Float16* __restrict__ Qh, const _Float16* __restrict__ Ql,
    const _Float16* __restrict__ Kh, const _Float16* __restrict__ Kl,
    const _Float16* __restrict__ Vh, const _Float16* __restrict__ Vl,
    _Float16* __restrict__ Oh, _Float16* __restrict__ Ol) {
  __shared__ _Float16 Ksh[32][72], Ksl[32][72];
  __shared__ _Float16 Vth[64][40], Vtl[64][40];
  __shared__ _Float16 Plh[4][16][40], Pll[4][16][40];
  const int qt = blockIdx.x, bh = blockIdx.y;
  const int b = bh >> 4, h = bh & 15;
  const int tid = threadIdx.x, w = tid >> 6, lane = tid & 63;
  const int rr = lane & 15, rg = lane >> 4;
  const size_t base = ((size_t)b * TSEQ) * DIM + (size_t)h * 64;
  const _Float16* qph = Qh + base; const _Float16* qpl = Ql + base;
  const _Float16* kph = Kh + base; const _Float16* kpl = Kl + base;
  const _Float16* vph = Vh + base; const _Float16* vpl = Vl + base;
  const int q0 = (qt << 6) + (w << 4);
  half8 qfh[2], qfl[2];
  {
    const size_t qoff = (size_t)(q0 + rr) * DIM + (rg << 3);
    qfh[0] = *(const half8*)&qph[qoff];
    qfl[0] = *(const half8*)&qpl[qoff];
    qfh[1] = *(const half8*)&qph[qoff + 32];
    qfl[1] = *(const half8*)&qpl[qoff + 32];
  }
  f32x4 oacc[4];
#pragma unroll
  for (int dg = 0; dg < 4; ++dg) oacc[dg] = (f32x4){0.f, 0.f, 0.f, 0.f};
  float mrow[4], lrow[4];
#pragma unroll
  for (int r = 0; r < 4; ++r) { mrow[r] = -INFINITY; lrow[r] = 0.0f; }
  const int ntiles = (qt << 1) + 2;
  const int sr = tid >> 3, ssx = tid & 7;
  for (int t = 0; t < ntiles; ++t) {
    const int kv0 = t << 5;
    {
      const size_t go = (size_t)(kv0 + sr) * DIM + (ssx << 3);
      *(half8*)&Ksh[sr][ssx << 3] = *(const half8*)&kph[go];
      *(half8*)&Ksl[sr][ssx << 3] = *(const half8*)&kpl[go];
      const half8 vvh = *(const half8*)&vph[go];
      const half8 vvl = *(const half8*)&vpl[go];
#pragma unroll
      for (int j = 0; j < 8; ++j) {
        Vth[(ssx << 3) + j][sr] = vvh[j];
        Vtl[(ssx << 3) + j][sr] = vvl[j];
      }
    }
    __syncthreads();
    f32x4 sacc[2];
    sacc[0] = (f32x4){0.f, 0.f, 0.f, 0.f};
    sacc[1] = (f32x4){0.f, 0.f, 0.f, 0.f};
#pragma unroll
    for (int sj = 0; sj < 2; ++sj) {
#pragma unroll
      for (int ks = 0; ks < 2; ++ks) {
        const int kr = (sj << 4) + rr;
        const half8 kfh = *(const half8*)&Ksh[kr][(ks << 5) + (rg << 3)];
        const half8 kfl = *(const half8*)&Ksl[kr][(ks << 5) + (rg << 3)];
        sacc[sj] = __builtin_amdgcn_mfma_f32_16x16x32_f16(qfh[ks], kfh, sacc[sj], 0, 0, 0);
        sacc[sj] = __builtin_amdgcn_mfma_f32_16x16x32_f16(qfh[ks], kfl, sacc[sj], 0, 0, 0);
        sacc[sj] = __builtin_amdgcn_mfma_f32_16x16x32_f16(qfl[ks], kfh, sacc[sj], 0, 0, 0);
      }
    }
    const float sscale = 0.125f / (SA * SA);
    float alpha[4];
#pragma unroll
    for (int r = 0; r < 4; ++r) {
      const int qg = q0 + (rg << 2) + r;
      float s0 = sacc[0][r] * sscale;
      float s1 = sacc[1][r] * sscale;
      if (kv0 + rr > qg) s0 = -INFINITY;
      if (kv0 + 16 + rr > qg) s1 = -INFINITY;
      float mx = fmaxf(s0, s1);
#pragma unroll
      for (int o = 1; o < 16; o <<= 1) mx = fmaxf(mx, __shfl_xor(mx, o));
      const float mn = fmaxf(mrow[r], mx);
      const float al = __expf(mrow[r] - mn);
      const float e0 = __expf(s0 - mn), e1 = __expf(s1 - mn);
      float rs = e0 + e1;
#pragma unroll
      for (int o = 1; o < 16; o <<= 1) rs += __shfl_xor(rs, o);
      lrow[r] = lrow[r] * al + rs;
      mrow[r] = mn;
      alpha[r] = al;
      const float p0 = e0 * SPC, p1 = e1 * SPC;
      const _Float16 p0h = (_Float16)p0, p1h = (_Float16)p1;
      Plh[w][(rg << 2) + r][rr] = p0h;
      Pll[w][(rg << 2) + r][rr] = (_Float16)(p0 - (float)p0h);
      Plh[w][(rg << 2) + r][16 + rr] = p1h;
      Pll[w][(rg << 2) + r][16 + rr] = (_Float16)(p1 - (float)p1h);
    }
#pragma unroll
    for (int dg = 0; dg < 4; ++dg)
#pragma unroll
      for (int r = 0; r < 4; ++r) oacc[dg][r] *= alpha[r];
    const half8 pfh = *(const half8*)&Plh[w][rr][rg << 3];
    const half8 pfl = *(const half8*)&Pll[w][rr][rg << 3];
#pragma unroll
    for (int dg = 0; dg < 4; ++dg) {
      const half8 vfh = *(const half8*)&Vth[(dg << 4) + rr][rg << 3];
      const half8 vfl = *(const half8*)&Vtl[(dg << 4) + rr][rg << 3];
      oacc[dg] = __builtin_amdgcn_mfma_f32_16x16x32_f16(pfh, vfh, oacc[dg], 0, 0, 0);
      oacc[dg] = __builtin_amdgcn_mfma_f32_16x16x32_f16(pfh, vfl, oacc[dg], 0, 0, 0);
      oacc[dg] = __builtin_amdgcn_mfma_f32_16x16x32_f16(pfl, vfh, oacc[dg], 0, 0, 0);
    }
    __syncthreads();
  }
  _Float16* oph = Oh + base; _Float16* opl = Ol + base;
#pragma unroll
  for (int dg = 0; dg < 4; ++dg)
#pragma unroll
    for (int r = 0; r < 4; ++r) {
      const int qg = q0 + (rg << 2) + r;
      const float ov = oacc[dg][r] / (lrow[r] * SPC);  // = out_true * SA
      const _Float16 hh = (_Float16)ov;
      oph[(size_t)qg * DIM + (dg << 4) + rr] = hh;
      opl[(size_t)qg * DIM + (dg << 4) + rr] = (_Float16)(ov - (float)hh);
    }
}

// ---------------- final combine ----------------
__global__ __launch_bounds__(256) void comb_k(float* __restrict__ outp,
                                              const float* __restrict__ moe) {
  const size_t i = (size_t)blockIdx.x * 256 + threadIdx.x;
  const int c4 = (int)(i & 255);
  float4 o = ((float4*)outp)[i];
  if (c4 >= 64) {
    const float4 m = ((const float4*)moe)[i];
    o.x += m.x; o.y += m.y; o.z += m.z; o.w += m.w;
  }
  ((float4*)outp)[i] = o;
}

extern "C" void kernel_launch(void* const* d_in, const int* in_sizes, int n_in,
                              void* d_out, int out_size, void* d_ws, size_t ws_size,
                              hipStream_t stream) {
  (void)in_sizes; (void)n_in; (void)out_size; (void)ws_size;
  const float* x    = (const float*)d_in[0];
  const float* n1w  = (const float*)d_in[1];
  const float* n2w  = (const float*)d_in[2];
  const float* wq   = (const float*)d_in[3];
  const float* wk   = (const float*)d_in[4];
  const float* wv   = (const float*)d_in[5];
  const float* wo   = (const float*)d_in[6];
  const float* qnw  = (const float*)d_in[7];
  const float* knw  = (const float*)d_in[8];
  const float* gw   = (const float*)d_in[9];
  const float* e0up = (const float*)d_in[10];
  const float* e0dn = (const float*)d_in[11];
  const float* e1w1 = (const float*)d_in[12];
  const float* e1w2 = (const float*)d_in[13];
  const float* e1dn = (const float*)d_in[14];
  const float* e2l1 = (const float*)d_in[15];
  const float* e2l2 = (const float*)d_in[16];
  const float* e2l3 = (const float*)d_in[17];
  const float* e2l4 = (const float*)d_in[18];
  const float* e3dn = (const float*)d_in[19];
  const float* e3up = (const float*)d_in[20];
  const float* e3o  = (const float*)d_in[21];
  float* outp = (float*)d_out;

  char* p = (char*)d_ws;
  auto alloc = [&](size_t bytes) { void* r = (void*)p; p += (bytes + 255) & ~(size_t)255; return r; };
  const size_t NC = (size_t)NTOK * DIM;
  const size_t NH2 = (size_t)NTOK * 2048;
  _Float16* hh = (_Float16*)alloc(NC * 2);
  _Float16* hl = (_Float16*)alloc(NC * 2);
  _Float16* qh = (_Float16*)alloc(NC * 2);
  _Float16* ql = (_Float16*)alloc(NC * 2);
  _Float16* kh = (_Float16*)alloc(NC * 2);
  _Float16* kl = (_Float16*)alloc(NC * 2);
  _Float16* vh = (_Float16*)alloc(NC * 2);
  _Float16* vl = (_Float16*)alloc(NC * 2);
  _Float16* wsh = (_Float16*)alloc((size_t)1024 * 1024 * 2);
  _Float16* wsl = (_Float16*)alloc((size_t)1024 * 1024 * 2);
  unsigned short* wsb = (unsigned short*)alloc((size_t)2048 * 2048 * 2);
  unsigned short* xfb = (unsigned short*)alloc(NC * 2);
  unsigned short* t0  = (unsigned short*)alloc(NH2 * 2);
  unsigned short* t1  = (unsigned short*)alloc(NH2 * 2);
  float* moe = (float*)alloc(NC * 4);
  float* wts = (float*)alloc((size_t)NTOK * 4 * 4);

  const int C2q = (1024 * 1024) / 4;  // fourths of a 1M-element weight
  const int CHq = (2048 * 1024) / 4;
  const int HHq = (2048 * 2048) / 4;

  // ---- attention path (fp16x2) ----
  rms_split_k<<<dim3(NTOK), dim3(256), 0, stream>>>(x, n1w, hh, hl);

  cvt_split_k<<<dim3(512), dim3(256), 0, stream>>>(wq, wsh, wsl, C2q, SW);
  gemm_split_k<0><<<dim3(8, 32), dim3(256), 0, stream>>>(hh, hl, wsh, wsl, 1024, 1024,
                                                         qh, ql, 1.0f / SW, nullptr, nullptr);
  cvt_split_k<<<dim3(512), dim3(256), 0, stream>>>(wk, wsh, wsl, C2q, SW);
  gemm_split_k<0><<<dim3(8, 32), dim3(256), 0, stream>>>(hh, hl, wsh, wsl, 1024, 1024,
                                                         kh, kl, 1.0f / SW, nullptr, nullptr);
  cvt_split_k<<<dim3(512), dim3(256), 0, stream>>>(wv, wsh, wsl, C2q, SW);
  gemm_split_k<0><<<dim3(8, 32), dim3(256), 0, stream>>>(hh, hl, wsh, wsl, 1024, 1024,
                                                         vh, vl, 1.0f / SW, nullptr, nullptr);

  qknorm_k<<<dim3(NTOK * NHEAD / 4), dim3(256), 0, stream>>>(qh, ql, qnw);
  qknorm_k<<<dim3(NTOK * NHEAD / 4), dim3(256), 0, stream>>>(kh, kl, knw);

  attn_k<<<dim3(16, 64), dim3(256), 0, stream>>>(qh, ql, kh, kl, vh, vl, hh, hl);  // ao -> h planes

  cvt_split_k<<<dim3(512), dim3(256), 0, stream>>>(wo, wsh, wsl, C2q, SW);
  gemm_split_k<1><<<dim3(8, 32), dim3(256), 0, stream>>>(hh, hl, wsh, wsl, 1024, 1024,
                                                         nullptr, nullptr, 1.0f / (SA * SW), x, outp);

  // ---- MoE ----
  rms_bf16_k<<<dim3(NTOK), dim3(256), 0, stream>>>(outp, n2w, xfb);
  gate_k<<<dim3(NTOK), dim3(256), 0, stream>>>(outp, n2w, gw, wts);

  // expert 0: gelu(xf@up^T)@down^T
  cvt_bf16_k<<<dim3(1024), dim3(256), 0, stream>>>(e0up, wsb, CHq);
  gemm_bf16_k<1, 0><<<dim3(16, 32), dim3(256), 0, stream>>>(xfb, wsb, 1024, 2048, t0, nullptr, nullptr, nullptr, 0);
  cvt_bf16_k<<<dim3(1024), dim3(256), 0, stream>>>(e0dn, wsb, CHq);
  gemm_bf16_k<0, 2><<<dim3(8, 32), dim3(256), 0, stream>>>(t0, wsb, 2048, 1024, nullptr, nullptr, moe, wts, 0);

  // expert 1: (silu(xf@w1^T) * (xf@w2^T)) @ down^T
  cvt_bf16_k<<<dim3(1024), dim3(256), 0, stream>>>(e1w2, wsb, CHq);
  gemm_bf16_k<0, 0><<<dim3(16, 32), dim3(256), 0, stream>>>(xfb, wsb, 1024, 2048, t0, nullptr, nullptr, nullptr, 0);
  cvt_bf16_k<<<dim3(1024), dim3(256), 0, stream>>>(e1w1, wsb, CHq);
  gemm_bf16_k<0, 1><<<dim3(16, 32), dim3(256), 0, stream>>>(xfb, wsb, 1024, 2048, t1, t0, nullptr, nullptr, 0);
  cvt_bf16_k<<<dim3(1024), dim3(256), 0, stream>>>(e1dn, wsb, CHq);
  gemm_bf16_k<0, 3><<<dim3(8, 32), dim3(256), 0, stream>>>(t1, wsb, 2048, 1024, nullptr, nullptr, moe, wts, 1);

  // expert 2: gelu(gelu(gelu(xf@l1)@l2)@l3)@l4
  cvt_bf16_k<<<dim3(1024), dim3(256), 0, stream>>>(e2l1, wsb, CHq);
  gemm_bf16_k<1, 0><<<dim3(16, 32), dim3(256), 0, stream>>>(xfb, wsb, 1024, 2048, t0, nullptr, nullptr, nullptr, 0);
  cvt_bf16_k<<<dim3(1024), dim3(256), 0, stream>>>(e2l2, wsb, HHq);
  gemm_bf16_k<1, 0><<<dim3(16, 32), dim3(256), 0, stream>>>(t0, wsb, 2048, 2048, t1, nullptr, nullptr, nullptr, 0);
  cvt_bf16_k<<<dim3(1024), dim3(256), 0, stream>>>(e2l3, wsb, HHq);
  gemm_bf16_k<1, 0><<<dim3(16, 32), dim3(256), 0, stream>>>(t1, wsb, 2048, 2048, t0, nullptr, nullptr, nullptr, 0);
  cvt_bf16_k<<<dim3(1024), dim3(256), 0, stream>>>(e2l4, wsb, CHq);
  gemm_bf16_k<0, 3><<<dim3(8, 32), dim3(256), 0, stream>>>(t0, wsb, 2048, 1024, nullptr, nullptr, moe, wts, 2);

  // expert 3: gelu(gelu(xf@down)@up)@out
  cvt_bf16_k<<<dim3(1024), dim3(256), 0, stream>>>(e3dn, wsb, C2q);
  gemm_bf16_k<1, 0><<<dim3(8, 32), dim3(256), 0, stream>>>(xfb, wsb, 1024, 1024, t1, nullptr, nullptr, nullptr, 0);
  cvt_bf16_k<<<dim3(1024), dim3(256), 0, stream>>>(e3up, wsb, CHq);
  gemm_bf16_k<1, 0><<<dim3(16, 32), dim3(256), 0, stream>>>(t1, wsb, 1024, 2048, t0, nullptr, nullptr, nullptr, 0);
  cvt_bf16_k<<<dim3(1024), dim3(256), 0, stream>>>(e3o, wsb, CHq);
  gemm_bf16_k<0, 3><<<dim3(8, 32), dim3(256), 0, stream>>>(t0, wsb, 2048, 1024, nullptr, nullptr, moe, wts, 3);

  comb_k<<<dim3(4096), dim3(256), 0, stream>>>(outp, moe);
}

// Round 2
// 743.329 us; speedup vs baseline: 1.1906x; 1.1906x over previous
//
#include <hip/hip_runtime.h>
#include <math.h>

#define DIM   1024
#define NTOK  4096
#define TSEQ  1024
#define NHEAD 16
#define MPROT 256
#define EPSR  1.1920929e-07f
#define SA    64.0f
#define SW    256.0f
#define SPC   64.0f

typedef __attribute__((ext_vector_type(8))) short          short8;
typedef __attribute__((ext_vector_type(8))) _Float16       half8;
typedef __attribute__((ext_vector_type(4))) _Float16       half4;
typedef __attribute__((ext_vector_type(4))) float          f32x4;
typedef __attribute__((ext_vector_type(4))) unsigned short us4;

static __device__ __forceinline__ float bf2f(unsigned short s) {
  union { unsigned int u; float f; } c; c.u = ((unsigned int)s) << 16; return c.f;
}
static __device__ __forceinline__ unsigned short f2bf(float f) {
  union { float f; unsigned int u; } c; c.f = f;
  return (unsigned short)((c.u + 0x7fffu + ((c.u >> 16) & 1u)) >> 16);
}
static __device__ __forceinline__ void gload16(void* lds, const void* g) {
  __builtin_amdgcn_global_load_lds(
      (__attribute__((address_space(1))) void*)const_cast<void*>(g),
      (__attribute__((address_space(3))) void*)lds, 16, 0, 0);
}

// ---------------- conversions ----------------
__global__ __launch_bounds__(256) void cvt_split_k(const float* __restrict__ s,
                                                   _Float16* __restrict__ hi,
                                                   _Float16* __restrict__ lo,
                                                   int n4, float scale) {
  int i = blockIdx.x * 256 + threadIdx.x;
  const int st = gridDim.x * 256;
  for (; i < n4; i += st) {
    const float4 v = ((const float4*)s)[i];
    float a0 = v.x * scale, a1 = v.y * scale, a2 = v.z * scale, a3 = v.w * scale;
    half4 hv, lv;
    _Float16 h0 = (_Float16)a0; hv[0] = h0; lv[0] = (_Float16)(a0 - (float)h0);
    _Float16 h1 = (_Float16)a1; hv[1] = h1; lv[1] = (_Float16)(a1 - (float)h1);
    _Float16 h2 = (_Float16)a2; hv[2] = h2; lv[2] = (_Float16)(a2 - (float)h2);
    _Float16 h3 = (_Float16)a3; hv[3] = h3; lv[3] = (_Float16)(a3 - (float)h3);
    ((half4*)hi)[i] = hv; ((half4*)lo)[i] = lv;
  }
}

// 4 attention weights split-converted in one launch into [4][1M] half planes
__global__ __launch_bounds__(256) void cvt_attn4_k(const float* __restrict__ wq,
                                                   const float* __restrict__ wk,
                                                   const float* __restrict__ wv,
                                                   const float* __restrict__ wo,
                                                   _Float16* __restrict__ dh,
                                                   _Float16* __restrict__ dl) {
  const int wi = blockIdx.y;
  const float* s = (wi == 0) ? wq : (wi == 1) ? wk : (wi == 2) ? wv : wo;
  const int i = blockIdx.x * 256 + threadIdx.x;
  const size_t off4 = ((size_t)wi << 20) >> 2;
  const float4 v = ((const float4*)s)[i];
  float a0 = v.x * SW, a1 = v.y * SW, a2 = v.z * SW, a3 = v.w * SW;
  half4 hv, lv;
  _Float16 h0 = (_Float16)a0; hv[0] = h0; lv[0] = (_Float16)(a0 - (float)h0);
  _Float16 h1 = (_Float16)a1; hv[1] = h1; lv[1] = (_Float16)(a1 - (float)h1);
  _Float16 h2 = (_Float16)a2; hv[2] = h2; lv[2] = (_Float16)(a2 - (float)h2);
  _Float16 h3 = (_Float16)a3; hv[3] = h3; lv[3] = (_Float16)(a3 - (float)h3);
  ((half4*)dh)[off4 + i] = hv; ((half4*)dl)[off4 + i] = lv;
}

__global__ __launch_bounds__(256) void cvt_bf16_k(const float* __restrict__ s,
                                                  unsigned short* __restrict__ d, int n4) {
  int i = blockIdx.x * 256 + threadIdx.x;
  const int st = gridDim.x * 256;
  for (; i < n4; i += st) {
    const float4 v = ((const float4*)s)[i];
    us4 o; o[0] = f2bf(v.x); o[1] = f2bf(v.y); o[2] = f2bf(v.z); o[3] = f2bf(v.w);
    ((us4*)d)[i] = o;
  }
}

// all 12 MoE weights -> bf16, one launch (batched path)
__global__ __launch_bounds__(256) void cvt_moe_all_k(
    const float* s0, const float* s1, const float* s2, const float* s3,
    const float* s4, const float* s5, const float* s6, const float* s7,
    const float* s8, const float* s9, const float* s10, const float* s11,
    unsigned short* __restrict__ dst) {
  const int n4tab[12] = {524288, 524288, 524288, 524288, 524288, 524288,
                         1048576, 1048576, 524288, 262144, 524288, 524288};
  const size_t offtab[12] = {0, 2097152, 4194304, 6291456, 8388608, 10485760,
                             12582912, 16777216, 20971520, 23068672, 24117248, 26214400};
  const int wi = blockIdx.y;
  const int i = blockIdx.x * 256 + threadIdx.x;
  if (i >= n4tab[wi]) return;
  const float* s;
  switch (wi) {
    case 0: s = s0; break; case 1: s = s1; break; case 2: s = s2; break;
    case 3: s = s3; break; case 4: s = s4; break; case 5: s = s5; break;
    case 6: s = s6; break; case 7: s = s7; break; case 8: s = s8; break;
    case 9: s = s9; break; case 10: s = s10; break; default: s = s11; break;
  }
  const float4 v = ((const float4*)s)[i];
  us4 o; o[0] = f2bf(v.x); o[1] = f2bf(v.y); o[2] = f2bf(v.z); o[3] = f2bf(v.w);
  ((us4*)(dst + offtab[wi]))[i] = o;
}

// ---------------- RMS norms ----------------
__global__ __launch_bounds__(256) void rms_split_k(const float* __restrict__ in,
                                                   const float* __restrict__ wgt,
                                                   _Float16* __restrict__ oh,
                                                   _Float16* __restrict__ ol) {
  const int row = blockIdx.x, tid = threadIdx.x;
  const float4 v = ((const float4*)(in + (size_t)row * DIM))[tid];
  float ss = v.x * v.x + v.y * v.y + v.z * v.z + v.w * v.w;
#pragma unroll
  for (int o = 32; o; o >>= 1) ss += __shfl_xor(ss, o);
  __shared__ float red[4];
  if ((tid & 63) == 0) red[tid >> 6] = ss;
  __syncthreads();
  const float sc = rsqrtf((red[0] + red[1] + red[2] + red[3]) * (1.0f / DIM) + EPSR) * SA;
  const float4 wv = ((const float4*)wgt)[tid];
  float a[4] = {v.x * sc * wv.x, v.y * sc * wv.y, v.z * sc * wv.z, v.w * sc * wv.w};
  half4 hv, lv;
#pragma unroll
  for (int j = 0; j < 4; ++j) {
    _Float16 hh = (_Float16)a[j]; hv[j] = hh; lv[j] = (_Float16)(a[j] - (float)hh);
  }
  ((half4*)(oh + (size_t)row * DIM))[tid] = hv;
  ((half4*)(ol + (size_t)row * DIM))[tid] = lv;
}

// fused RMSNorm(bf16 out) + gate logits/softmax/top-2
__global__ __launch_bounds__(256) void rmsgate_k(const float* __restrict__ x2,
                                                 const float* __restrict__ n2w,
                                                 const float* __restrict__ gw,
                                                 unsigned short* __restrict__ xfb,
                                                 float* __restrict__ wts) {
  const int row = blockIdx.x, tid = threadIdx.x;
  const float4 v = ((const float4*)(x2 + (size_t)row * DIM))[tid];
  float ss = v.x * v.x + v.y * v.y + v.z * v.z + v.w * v.w;
#pragma unroll
  for (int o = 32; o; o >>= 1) ss += __shfl_xor(ss, o);
  __shared__ float red[4];
  __shared__ float redE[4][4];
  const int w = tid >> 6, lane = tid & 63;
  if (lane == 0) red[w] = ss;
  __syncthreads();
  const float sc = rsqrtf((red[0] + red[1] + red[2] + red[3]) * (1.0f / DIM) + EPSR);
  const float4 nw = ((const float4*)n2w)[tid];
  const float xn0 = v.x * sc * nw.x, xn1 = v.y * sc * nw.y;
  const float xn2 = v.z * sc * nw.z, xn3 = v.w * sc * nw.w;
  us4 ob; ob[0] = f2bf(xn0); ob[1] = f2bf(xn1); ob[2] = f2bf(xn2); ob[3] = f2bf(xn3);
  ((us4*)(xfb + (size_t)row * DIM))[tid] = ob;
#pragma unroll
  for (int e = 0; e < 4; ++e) {
    const float4 g = ((const float4*)(gw + (size_t)e * DIM))[tid];
    float d = xn0 * g.x + xn1 * g.y + xn2 * g.z + xn3 * g.w;
#pragma unroll
    for (int o = 32; o; o >>= 1) d += __shfl_xor(d, o);
    if (lane == 0) redE[w][e] = d;
  }
  __syncthreads();
  if (tid == 0) {
    float lg[4];
#pragma unroll
    for (int e = 0; e < 4; ++e) lg[e] = redE[0][e] + redE[1][e] + redE[2][e] + redE[3][e];
    const float mx = fmaxf(fmaxf(lg[0], lg[1]), fmaxf(lg[2], lg[3]));
    float pe[4]; float sum = 0.0f;
#pragma unroll
    for (int e = 0; e < 4; ++e) { pe[e] = __expf(lg[e] - mx); sum += pe[e]; }
#pragma unroll
    for (int e = 0; e < 4; ++e) pe[e] /= sum;
    int i1 = 0;
    for (int e = 1; e < 4; ++e) if (pe[e] > pe[i1]) i1 = e;
    int i2 = -1;
    for (int e = 0; e < 4; ++e) { if (e == i1) continue; if (i2 < 0 || pe[e] > pe[i2]) i2 = e; }
    const float s2 = pe[i1] + pe[i2] + 1e-8f;
    float o[4] = {0.f, 0.f, 0.f, 0.f};
    o[i1] = pe[i1] / s2; o[i2] = pe[i2] / s2;
    float4 r; r.x = o[0]; r.y = o[1]; r.z = o[2]; r.w = o[3];
    *(float4*)(wts + (size_t)row * 4) = r;
  }
}

// per (token,head) RMS over 64 dims; y=0 -> Q planes, y=1 -> K planes
__global__ __launch_bounds__(256) void qknorm2_k(_Float16* __restrict__ qh,
                                                 _Float16* __restrict__ ql,
                                                 _Float16* __restrict__ kh,
                                                 _Float16* __restrict__ kl,
                                                 const float* __restrict__ qnw,
                                                 const float* __restrict__ knw) {
  _Float16* ph; _Float16* pl; const float* wgt;
  if (blockIdx.y == 0) { ph = qh; pl = ql; wgt = qnw; }
  else { ph = kh; pl = kl; wgt = knw; }
  const int idx = (blockIdx.x << 2) + (threadIdx.x >> 6);
  const int lane = threadIdx.x & 63;
  const size_t off = ((size_t)idx << 6) + lane;
  const float v = (float)ph[off] + (float)pl[off];
  float ss = v * v;
#pragma unroll
  for (int o = 32; o; o >>= 1) ss += __shfl_xor(ss, o);
  const float sc = rsqrtf(ss * (1.0f / (64.0f * SA * SA)) + EPSR);
  const float nv = v * sc * wgt[lane];
  _Float16 hh = (_Float16)nv;
  ph[off] = hh; pl[off] = (_Float16)(nv - (float)hh);
}

// ---------------- bf16 GEMM: out = epilogue(A[M,K] @ W[F,K]^T) ----------------
// ACT: 0=none 1=gelu
// EP: 0=store bf16, 1=silu(v)*other->bf16, 2=moe first(=), 3=moe acc(+=),
//     4=final: outf += mask(moein + wt*v)
template <int ACT, int EP>
__global__ __launch_bounds__(256, 2) void gemm_bf16_k(
    const unsigned short* __restrict__ A, const unsigned short* __restrict__ Bw,
    int K, int F,
    unsigned short* __restrict__ outb, const unsigned short* __restrict__ other,
    float* __restrict__ outf, const float* __restrict__ wts, int expert,
    const float* __restrict__ moein) {
  __shared__ unsigned short As[2][128][64];
  __shared__ unsigned short Bs[2][128][64];
  const int tid = threadIdx.x;
  const int w = tid >> 6, lane = tid & 63;
  const int wr = ((w >> 1) << 6), wc = ((w & 1) << 6);
  // XCD-chunked swizzle: each XCD gets a contiguous row-strip of the grid
  int nlin = blockIdx.y * gridDim.x + blockIdx.x;
  const int tot = gridDim.x * gridDim.y;
  nlin = (nlin & 7) * (tot >> 3) + (nlin >> 3);
  const int lgx = 31 - __clz(gridDim.x);
  const int m0 = (nlin >> lgx) << 7, n0 = (nlin & (gridDim.x - 1)) << 7;
  const int rr = lane & 15, kgl = lane >> 4;
  const int srow = tid >> 3, sslot = tid & 7;

  f32x4 acc[4][4];
#pragma unroll
  for (int a_ = 0; a_ < 4; ++a_)
#pragma unroll
    for (int b_ = 0; b_ < 4; ++b_) acc[a_][b_] = (f32x4){0.f, 0.f, 0.f, 0.f};

  const int KT = K >> 6;
  auto stage = [&](int buf, int kt) {
    const int k0 = kt << 6;
#pragma unroll
    for (int i = 0; i < 4; ++i) {
      const int r = (i << 5) + srow;
      const int ls = sslot ^ (r & 7);
      gload16(&As[buf][(i << 5) + (w << 3)][0], A + (size_t)(m0 + r) * K + k0 + (ls << 3));
      gload16(&Bs[buf][(i << 5) + (w << 3)][0], Bw + (size_t)(n0 + r) * K + k0 + (ls << 3));
    }
  };
  stage(0, 0);
  __syncthreads();
  for (int kt = 0; kt < KT; ++kt) {
    const int cur = kt & 1;
    if (kt + 1 < KT) stage(cur ^ 1, kt + 1);
    short8 af[4][2], bfr[4][2];
#pragma unroll
    for (int f = 0; f < 4; ++f) {
#pragma unroll
      for (int ks = 0; ks < 2; ++ks) {
        const int row = wr + (f << 4) + rr;
        const int kg = (ks << 2) + kgl;
        af[f][ks] = *(const short8*)&As[cur][row][(kg ^ (row & 7)) << 3];
        const int col = wc + (f << 4) + rr;
        bfr[f][ks] = *(const short8*)&Bs[cur][col][(kg ^ (col & 7)) << 3];
      }
    }
#pragma unroll
    for (int fi = 0; fi < 4; ++fi)
#pragma unroll
      for (int fj = 0; fj < 4; ++fj)
#pragma unroll
        for (int ks = 0; ks < 2; ++ks)
          acc[fi][fj] = __builtin_amdgcn_mfma_f32_16x16x32_bf16(
              af[fi][ks], bfr[fj][ks], acc[fi][fj], 0, 0, 0);
    __syncthreads();
  }
#pragma unroll
  for (int fi = 0; fi < 4; ++fi)
#pragma unroll
    for (int fj = 0; fj < 4; ++fj) {
      const int col = n0 + wc + (fj << 4) + rr;
#pragma unroll
      for (int r = 0; r < 4; ++r) {
        const int row = m0 + wr + (fi << 4) + (kgl << 2) + r;
        float v = acc[fi][fj][r];
        if (ACT == 1) v = 0.5f * v * (1.0f + erff(v * 0.70710678118654752f));
        const size_t off = (size_t)row * F + col;
        if (EP == 0) {
          outb[off] = f2bf(v);
        } else if (EP == 1) {
          const float sv = v / (1.0f + __expf(-v));
          outb[off] = f2bf(sv * bf2f(other[off]));
        } else if (EP == 2) {
          outf[off] = wts[(size_t)row * 4 + expert] * v;
        } else if (EP == 3) {
          outf[off] += wts[(size_t)row * 4 + expert] * v;
        } else {
          if (col >= MPROT) outf[off] += moein[off] + wts[(size_t)row * 4 + expert] * v;
        }
      }
    }
}

// ---------------- fp16x2 split GEMM (3-term) ----------------
// EP: 0 = write split pair; 1 = fp32: resid + masked(v); 2 = write V^T split planes
template <int EP>
__global__ __launch_bounds__(256, 2) void gemm_split_k(
    const _Float16* __restrict__ Ah, const _Float16* __restrict__ Al,
    const _Float16* __restrict__ Bh, const _Float16* __restrict__ Bl,
    int K, int F,
    _Float16* __restrict__ Oh, _Float16* __restrict__ Ol, float oscale,
    const float* __restrict__ resid, float* __restrict__ outf) {
  __shared__ _Float16 AsH[2][128][32], AsL[2][128][32];
  __shared__ _Float16 BsH[2][128][32], BsL[2][128][32];
  const int tid = threadIdx.x;
  const int w = tid >> 6, lane = tid & 63;
  const int wr = ((w >> 1) << 6), wc = ((w & 1) << 6);
  int nlin = blockIdx.y * gridDim.x + blockIdx.x;
  const int tot = gridDim.x * gridDim.y;
  nlin = (nlin & 7) * (tot >> 3) + (nlin >> 3);
  const int lgx = 31 - __clz(gridDim.x);
  const int m0 = (nlin >> lgx) << 7, n0 = (nlin & (gridDim.x - 1)) << 7;
  const int rr = lane & 15, kgl = lane >> 4;
  const int srow = tid >> 2, sslot = tid & 3;

  f32x4 acc[4][4];
#pragma unroll
  for (int a_ = 0; a_ < 4; ++a_)
#pragma unroll
    for (int b_ = 0; b_ < 4; ++b_) acc[a_][b_] = (f32x4){0.f, 0.f, 0.f, 0.f};

  const int KT = K >> 5;
  auto stage = [&](int buf, int kt) {
    const int k0 = kt << 5;
#pragma unroll
    for (int i = 0; i < 2; ++i) {
      const int r = (i << 6) + srow;
      const int ls = sslot ^ ((r >> 1) & 3);
      const size_t ga = (size_t)(m0 + r) * K + k0 + (ls << 3);
      const size_t gb = (size_t)(n0 + r) * K + k0 + (ls << 3);
      const int lr = (i << 6) + (w << 4);
      gload16(&AsH[buf][lr][0], Ah + ga);
      gload16(&AsL[buf][lr][0], Al + ga);
      gload16(&BsH[buf][lr][0], Bh + gb);
      gload16(&BsL[buf][lr][0], Bl + gb);
    }
  };
  stage(0, 0);
  __syncthreads();
  for (int kt = 0; kt < KT; ++kt) {
    const int cur = kt & 1;
    if (kt + 1 < KT) stage(cur ^ 1, kt + 1);
    half8 ah[4], al[4], bh[4], bl[4];
#pragma unroll
    for (int f = 0; f < 4; ++f) {
      const int row = wr + (f << 4) + rr;
      const int pa = (kgl ^ ((row >> 1) & 3)) << 3;
      ah[f] = *(const half8*)&AsH[cur][row][pa];
      al[f] = *(const half8*)&AsL[cur][row][pa];
      const int col = wc + (f << 4) + rr;
      const int pb = (kgl ^ ((col >> 1) & 3)) << 3;
      bh[f] = *(const half8*)&BsH[cur][col][pb];
      bl[f] = *(const half8*)&BsL[cur][col][pb];
    }
#pragma unroll
    for (int fi = 0; fi < 4; ++fi)
#pragma unroll
      for (int fj = 0; fj < 4; ++fj) {
        acc[fi][fj] = __builtin_amdgcn_mfma_f32_16x16x32_f16(ah[fi], bh[fj], acc[fi][fj], 0, 0, 0);
        acc[fi][fj] = __builtin_amdgcn_mfma_f32_16x16x32_f16(ah[fi], bl[fj], acc[fi][fj], 0, 0, 0);
        acc[fi][fj] = __builtin_amdgcn_mfma_f32_16x16x32_f16(al[fi], bh[fj], acc[fi][fj], 0, 0, 0);
      }
    __syncthreads();
  }
#pragma unroll
  for (int fi = 0; fi < 4; ++fi)
#pragma unroll
    for (int fj = 0; fj < 4; ++fj) {
      const int col = n0 + wc + (fj << 4) + rr;
      const int rowb = m0 + wr + (fi << 4) + (kgl << 2);
      if (EP == 2) {
        half4 h4, l4;
#pragma unroll
        for (int r = 0; r < 4; ++r) {
          const float v = acc[fi][fj][r] * oscale;
          const _Float16 hh2 = (_Float16)v;
          h4[r] = hh2; l4[r] = (_Float16)(v - (float)hh2);
        }
        const size_t vt = ((size_t)((rowb >> 10) << 4) + (size_t)(col >> 6)) * 65536 +
                          (size_t)(col & 63) * 1024 + (size_t)(rowb & 1023);
        *(half4*)&Oh[vt] = h4;
        *(half4*)&Ol[vt] = l4;
      } else {
#pragma unroll
        for (int r = 0; r < 4; ++r) {
          const int row = rowb + r;
          const size_t off = (size_t)row * F + col;
          const float v = acc[fi][fj][r] * oscale;
          if (EP == 0) {
            const _Float16 hh2 = (_Float16)v;
            Oh[off] = hh2; Ol[off] = (_Float16)(v - (float)hh2);
          } else {
            outf[off] = resid[off] + (col >= MPROT ? v : 0.0f);
          }
        }
      }
    }
}

// ---------------- flash attention, causal, fp16x2 split, swapped-QK ----------------
// grid: 512 linear blocks; block = 4 waves x 32 q-rows = 128 q-rows; KVBLK=32 dbuf
__global__ __launch_bounds__(256, 2) void attn_k(
    const _Float16* __restrict__ Qh, const _Float16* __restrict__ Ql,
    const _Float16* __restrict__ Kh, const _Float16* __restrict__ Kl,
    const _Float16* __restrict__ Vth, const _Float16* __restrict__ Vtl,
    _Float16* __restrict__ Oh, _Float16* __restrict__ Ol) {
  __shared__ _Float16 Ksh[2][32][64], Ksl[2][32][64];
  __shared__ _Float16 Vsh[2][64][40], Vsl[2][64][40];
  __shared__ _Float16 Plh[4][16][40], Pll[4][16][40];
  const int n = blockIdx.x;
  const int qt = n >> 6;                              // 0..7
  const int bh = ((n & 7) << 3) | ((n >> 3) & 7);     // XCD-local head groups
  const int b = bh >> 4, h = bh & 15;
  const int tid = threadIdx.x, w = tid >> 6, lane = tid & 63;
  const int rr = lane & 15, rg = lane >> 4;
  const size_t tokbase = (size_t)b * TSEQ;
  const int hcol = h << 6;
  const size_t vtbase = (size_t)bh << 16;
  const int q0w = (qt << 7) + (w << 5);
  const float sscale = 0.125f / (SA * SA);

  // Q fragments in registers (B-operand layout)
  half8 qfh[2][2], qfl[2][2];
#pragma unroll
  for (int qf = 0; qf < 2; ++qf)
#pragma unroll
    for (int ks = 0; ks < 2; ++ks) {
      const size_t off = (tokbase + q0w + (qf << 4) + rr) * DIM + hcol + (ks << 5) + (rg << 3);
      qfh[qf][ks] = *(const half8*)&Qh[off];
      qfl[qf][ks] = *(const half8*)&Ql[off];
    }

  f32x4 oacc[2][4];
#pragma unroll
  for (int qf = 0; qf < 2; ++qf)
#pragma unroll
    for (int dg = 0; dg < 4; ++dg) oacc[qf][dg] = (f32x4){0.f, 0.f, 0.f, 0.f};
  float mreg[2] = {-INFINITY, -INFINITY}, lreg[2] = {0.f, 0.f};

  const int kr = (w << 3) + (lane >> 3);   // staged K row (0..31 over block)
  const int kswz = ((lane & 7) ^ (kr & 7)) << 3;
  const int vr = tid >> 2;                 // V^T d-row (0..63)
  const int vs = (tid & 3) << 3;           // k-offset in halves

  const int ntiles = (qt + 1) << 2;

  // prologue: stage tile 0
  {
    gload16(&Ksh[0][w << 3][0], &Kh[(tokbase + kr) * DIM + hcol + kswz]);
    gload16(&Ksl[0][w << 3][0], &Kl[(tokbase + kr) * DIM + hcol + kswz]);
    const half8 vvh = *(const half8*)&Vth[vtbase + (size_t)vr * TSEQ + vs];
    const half8 vvl = *(const half8*)&Vtl[vtbase + (size_t)vr * TSEQ + vs];
    *(half8*)&Vsh[0][vr][vs] = vvh;
    *(half8*)&Vsl[0][vr][vs] = vvl;
    __syncthreads();
  }

  for (int t = 0; t < ntiles; ++t) {
    const int cur = t & 1;
    const int kv0 = t << 5;
    const bool havenext = (t + 1 < ntiles);
    half8 nvh, nvl;
    if (havenext) {
      const int kn = kv0 + 32;
      gload16(&Ksh[cur ^ 1][w << 3][0], &Kh[(tokbase + kn + kr) * DIM + hcol + kswz]);
      gload16(&Ksl[cur ^ 1][w << 3][0], &Kl[(tokbase + kn + kr) * DIM + hcol + kswz]);
      nvh = *(const half8*)&Vth[vtbase + (size_t)vr * TSEQ + kn + vs];
      nvl = *(const half8*)&Vtl[vtbase + (size_t)vr * TSEQ + kn + vs];
    }
    if (kv0 <= q0w + 31) {
      half8 kfh[2][2], kfl[2][2];
#pragma unroll
      for (int kt = 0; kt < 2; ++kt)
#pragma unroll
        for (int ks = 0; ks < 2; ++ks) {
          const int row = (kt << 4) + rr;
          const int sw = ((((ks << 2) + rg)) ^ (row & 7)) << 3;
          kfh[kt][ks] = *(const half8*)&Ksh[cur][row][sw];
          kfl[kt][ks] = *(const half8*)&Ksl[cur][row][sw];
        }
#pragma unroll
      for (int qf = 0; qf < 2; ++qf) {
        if (kv0 > q0w + (qf << 4) + 15) continue;
        f32x4 st[2];
        st[0] = (f32x4){0.f, 0.f, 0.f, 0.f};
        st[1] = (f32x4){0.f, 0.f, 0.f, 0.f};
#pragma unroll
        for (int kt = 0; kt < 2; ++kt)
#pragma unroll
          for (int ks = 0; ks < 2; ++ks) {
            st[kt] = __builtin_amdgcn_mfma_f32_16x16x32_f16(kfh[kt][ks], qfh[qf][ks], st[kt], 0, 0, 0);
            st[kt] = __builtin_amdgcn_mfma_f32_16x16x32_f16(kfh[kt][ks], qfl[qf][ks], st[kt], 0, 0, 0);
            st[kt] = __builtin_amdgcn_mfma_f32_16x16x32_f16(kfl[kt][ks], qfh[qf][ks], st[kt], 0, 0, 0);
          }
        const int qg = q0w + (qf << 4) + rr;
        float s[2][4]; float mx = -INFINITY;
#pragma unroll
        for (int kt = 0; kt < 2; ++kt)
#pragma unroll
          for (int r = 0; r < 4; ++r) {
            float sv = st[kt][r] * sscale;
            if (kv0 + (kt << 4) + (rg << 2) + r > qg) sv = -INFINITY;
            s[kt][r] = sv; mx = fmaxf(mx, sv);
          }
        mx = fmaxf(mx, __shfl_xor(mx, 16));
        mx = fmaxf(mx, __shfl_xor(mx, 32));
        const float mn = fmaxf(mreg[qf], mx);
        const float al = __expf(mreg[qf] - mn);
        mreg[qf] = mn;
        float p[2][4]; float rs = 0.f;
#pragma unroll
        for (int kt = 0; kt < 2; ++kt)
#pragma unroll
          for (int r = 0; r < 4; ++r) { p[kt][r] = __expf(s[kt][r] - mn); rs += p[kt][r]; }
        rs += __shfl_xor(rs, 16);
        rs += __shfl_xor(rs, 32);
        lreg[qf] = lreg[qf] * al + rs;
        // packed P store (k-contiguous per lane)
#pragma unroll
        for (int kt = 0; kt < 2; ++kt) {
          half4 h4, l4;
#pragma unroll
          for (int r = 0; r < 4; ++r) {
            const float pv = p[kt][r] * SPC;
            const _Float16 ph = (_Float16)pv;
            h4[r] = ph; l4[r] = (_Float16)(pv - (float)ph);
          }
          *(half4*)&Plh[w][rr][(kt << 4) + (rg << 2)] = h4;
          *(half4*)&Pll[w][rr][(kt << 4) + (rg << 2)] = l4;
        }
        // rescale running O by alpha (broadcast per output-row)
        float alr[4];
#pragma unroll
        for (int r = 0; r < 4; ++r) alr[r] = __shfl(al, (lane & 48) | ((rg << 2) + r));
#pragma unroll
        for (int dg = 0; dg < 4; ++dg)
#pragma unroll
          for (int r = 0; r < 4; ++r) oacc[qf][dg][r] *= alr[r];
        // PV
        const half8 pah = *(const half8*)&Plh[w][rr][rg << 3];
        const half8 pal = *(const half8*)&Pll[w][rr][rg << 3];
#pragma unroll
        for (int dg = 0; dg < 4; ++dg) {
          const half8 vfh2 = *(const half8*)&Vsh[cur][(dg << 4) + rr][rg << 3];
          const half8 vfl2 = *(const half8*)&Vsl[cur][(dg << 4) + rr][rg << 3];
          oacc[qf][dg] = __builtin_amdgcn_mfma_f32_16x16x32_f16(pah, vfh2, oacc[qf][dg], 0, 0, 0);
          oacc[qf][dg] = __builtin_amdgcn_mfma_f32_16x16x32_f16(pah, vfl2, oacc[qf][dg], 0, 0, 0);
          oacc[qf][dg] = __builtin_amdgcn_mfma_f32_16x16x32_f16(pal, vfh2, oacc[qf][dg], 0, 0, 0);
        }
      }
    }
    if (havenext) {
      *(half8*)&Vsh[cur ^ 1][vr][vs] = nvh;
      *(half8*)&Vsl[cur ^ 1][vr][vs] = nvl;
    }
    __syncthreads();
  }
  // epilogue
#pragma unroll
  for (int qf = 0; qf < 2; ++qf) {
    float li[4];
#pragma unroll
    for (int r = 0; r < 4; ++r)
      li[r] = __shfl(lreg[qf], (lane & 48) | ((rg << 2) + r));
#pragma unroll
    for (int dg = 0; dg < 4; ++dg)
#pragma unroll
      for (int r = 0; r < 4; ++r) {
        const int qloc = (rg << 2) + r;
        const float ov = oacc[qf][dg][r] / (li[r] * SPC);   // = out_true * SA
        const _Float16 hh2 = (_Float16)ov;
        const size_t off = (tokbase + q0w + (qf << 4) + qloc) * DIM + hcol + (dg << 4) + rr;
        Oh[off] = hh2;
        Ol[off] = (_Float16)(ov - (float)hh2);
      }
  }
}

extern "C" void kernel_launch(void* const* d_in, const int* in_sizes, int n_in,
                              void* d_out, int out_size, void* d_ws, size_t ws_size,
                              hipStream_t stream) {
  (void)in_sizes; (void)n_in; (void)out_size;
  const float* x    = (const float*)d_in[0];
  const float* n1w  = (const float*)d_in[1];
  const float* n2w  = (const float*)d_in[2];
  const float* wq   = (const float*)d_in[3];
  const float* wk   = (const float*)d_in[4];
  const float* wv   = (const float*)d_in[5];
  const float* wo   = (const float*)d_in[6];
  const float* qnw  = (const float*)d_in[7];
  const float* knw  = (const float*)d_in[8];
  const float* gw   = (const float*)d_in[9];
  const float* moesrc[12] = {
    (const float*)d_in[10], (const float*)d_in[11],  // e0up e0dn
    (const float*)d_in[12], (const float*)d_in[13], (const float*)d_in[14],  // e1w1 e1w2 e1dn
    (const float*)d_in[15], (const float*)d_in[16], (const float*)d_in[17], (const float*)d_in[18],  // e2
    (const float*)d_in[19], (const float*)d_in[20], (const float*)d_in[21]   // e3
  };
  float* outp = (float*)d_out;

  char* p = (char*)d_ws;
  auto alloc = [&](size_t bytes) { void* r = (void*)p; p += (bytes + 255) & ~(size_t)255; return r; };
  const size_t NC = (size_t)NTOK * DIM;
  const size_t NH2 = (size_t)NTOK * 2048;
  _Float16* hh = (_Float16*)alloc(NC * 2);
  _Float16* hl = (_Float16*)alloc(NC * 2);
  _Float16* qh = (_Float16*)alloc(NC * 2);
  _Float16* ql = (_Float16*)alloc(NC * 2);
  _Float16* kh = (_Float16*)alloc(NC * 2);
  _Float16* kl = (_Float16*)alloc(NC * 2);
  _Float16* vth = (_Float16*)alloc(NC * 2);
  _Float16* vtl = (_Float16*)alloc(NC * 2);
  unsigned short* xfb = (unsigned short*)alloc(NC * 2);
  unsigned short* t0  = (unsigned short*)alloc(NH2 * 2);
  unsigned short* t1  = (unsigned short*)alloc(NH2 * 2);
  float* moe = (float*)alloc(NC * 4);
  float* wts = (float*)alloc((size_t)NTOK * 4 * 4);

  const size_t MOEW_ELEMS = 28311552;  // 12 weights, bf16
  const size_t need_batched = (size_t)(p - (char*)d_ws) + (size_t)4 * 1024 * 1024 * 2 * 2 +
                              MOEW_ELEMS * 2 + (size_t)(1 << 20);
  const bool batched = (ws_size >= need_batched);

  _Float16 *awh = nullptr, *awl = nullptr;      // [4][1M] attn weight split planes
  unsigned short* moeW = nullptr;               // 12 MoE weights bf16
  _Float16 *wsh = nullptr, *wsl = nullptr;      // fallback rotating split weight
  unsigned short* wsb = nullptr;                // fallback rotating bf16 weight
  if (batched) {
    awh = (_Float16*)alloc((size_t)4 * 1024 * 1024 * 2);
    awl = (_Float16*)alloc((size_t)4 * 1024 * 1024 * 2);
    moeW = (unsigned short*)alloc(MOEW_ELEMS * 2);
  } else {
    wsh = (_Float16*)alloc((size_t)1024 * 1024 * 2);
    wsl = (_Float16*)alloc((size_t)1024 * 1024 * 2);
    wsb = (unsigned short*)alloc((size_t)2048 * 2048 * 2);
  }

  const size_t moff[12] = {0, 2097152, 4194304, 6291456, 8388608, 10485760,
                           12582912, 16777216, 20971520, 23068672, 24117248, 26214400};
  const int C2q = (1024 * 1024) / 4;

  // ---- weight conversions ----
  const _Float16 *wqh, *wql, *wkh, *wkl, *wvh, *wvl, *woh, *wol;
  if (batched) {
    cvt_attn4_k<<<dim3(1024, 4), dim3(256), 0, stream>>>(wq, wk, wv, wo, awh, awl);
    cvt_moe_all_k<<<dim3(4096, 12), dim3(256), 0, stream>>>(
        moesrc[0], moesrc[1], moesrc[2], moesrc[3], moesrc[4], moesrc[5],
        moesrc[6], moesrc[7], moesrc[8], moesrc[9], moesrc[10], moesrc[11], moeW);
    wqh = awh;            wql = awl;
    wkh = awh + (1 << 20); wkl = awl + (1 << 20);
    wvh = awh + (2 << 20); wvl = awl + (2 << 20);
    woh = awh + (3 << 20); wol = awl + (3 << 20);
  } else {
    wqh = wkh = wvh = woh = wsh; wql = wkl = wvl = wol = wsl;
  }
  auto mw = [&](int i) -> const unsigned short* { return batched ? moeW + moff[i] : wsb; };
  auto cvb = [&](int i, int n4) {
    if (!batched) cvt_bf16_k<<<dim3(1024), dim3(256), 0, stream>>>(moesrc[i], wsb, n4);
  };

  // ---- attention path (fp16x2) ----
  rms_split_k<<<dim3(NTOK), dim3(256), 0, stream>>>(x, n1w, hh, hl);

  if (!batched) cvt_split_k<<<dim3(512), dim3(256), 0, stream>>>(wq, wsh, wsl, C2q, SW);
  gemm_split_k<0><<<dim3(8, 32), dim3(256), 0, stream>>>(hh, hl, wqh, wql, 1024, 1024,
                                                         qh, ql, 1.0f / SW, nullptr, nullptr);
  if (!batched) cvt_split_k<<<dim3(512), dim3(256), 0, stream>>>(wk, wsh, wsl, C2q, SW);
  gemm_split_k<0><<<dim3(8, 32), dim3(256), 0, stream>>>(hh, hl, wkh, wkl, 1024, 1024,
                                                         kh, kl, 1.0f / SW, nullptr, nullptr);
  if (!batched) cvt_split_k<<<dim3(512), dim3(256), 0, stream>>>(wv, wsh, wsl, C2q, SW);
  gemm_split_k<2><<<dim3(8, 32), dim3(256), 0, stream>>>(hh, hl, wvh, wvl, 1024, 1024,
                                                         vth, vtl, 1.0f / SW, nullptr, nullptr);

  qknorm2_k<<<dim3(NTOK * NHEAD / 4, 2), dim3(256), 0, stream>>>(qh, ql, kh, kl, qnw, knw);

  attn_k<<<dim3(512), dim3(256), 0, stream>>>(qh, ql, kh, kl, vth, vtl, hh, hl);

  if (!batched) cvt_split_k<<<dim3(512), dim3(256), 0, stream>>>(wo, wsh, wsl, C2q, SW);
  gemm_split_k<1><<<dim3(8, 32), dim3(256), 0, stream>>>(hh, hl, woh, wol, 1024, 1024,
                                                         nullptr, nullptr, 1.0f / (SA * SW), x, outp);

  // ---- MoE ----
  rmsgate_k<<<dim3(NTOK), dim3(256), 0, stream>>>(outp, n2w, gw, xfb, wts);

  // expert 0
  cvb(0, 524288);
  gemm_bf16_k<1, 0><<<dim3(16, 32), dim3(256), 0, stream>>>(xfb, mw(0), 1024, 2048, t0, nullptr, nullptr, nullptr, 0, nullptr);
  cvb(1, 524288);
  gemm_bf16_k<0, 2><<<dim3(8, 32), dim3(256), 0, stream>>>(t0, mw(1), 2048, 1024, nullptr, nullptr, moe, wts, 0, nullptr);
  // expert 1
  cvb(3, 524288);
  gemm_bf16_k<0, 0><<<dim3(16, 32), dim3(256), 0, stream>>>(xfb, mw(3), 1024, 2048, t0, nullptr, nullptr, nullptr, 0, nullptr);
  cvb(2, 524288);
  gemm_bf16_k<0, 1><<<dim3(16, 32), dim3(256), 0, stream>>>(xfb, mw(2), 1024, 2048, t1, t0, nullptr, nullptr, 0, nullptr);
  cvb(4, 524288);
  gemm_bf16_k<0, 3><<<dim3(8, 32), dim3(256), 0, stream>>>(t1, mw(4), 2048, 1024, nullptr, nullptr, moe, wts, 1, nullptr);
  // expert 2
  cvb(5, 524288);
  gemm_bf16_k<1, 0><<<dim3(16, 32), dim3(256), 0, stream>>>(xfb, mw(5), 1024, 2048, t0, nullptr, nullptr, nullptr, 0, nullptr);
  cvb(6, 1048576);
  gemm_bf16_k<1, 0><<<dim3(16, 32), dim3(256), 0, stream>>>(t0, mw(6), 2048, 2048, t1, nullptr, nullptr, nullptr, 0, nullptr);
  cvb(7, 1048576);
  gemm_bf16_k<1, 0><<<dim3(16, 32), dim3(256), 0, stream>>>(t1, mw(7), 2048, 2048, t0, nullptr, nullptr, nullptr, 0, nullptr);
  cvb(8, 524288);
  gemm_bf16_k<0, 3><<<dim3(8, 32), dim3(256), 0, stream>>>(t0, mw(8), 2048, 1024, nullptr, nullptr, moe, wts, 2, nullptr);
  // expert 3 (final GEMM folds masked combine into d_out)
  cvb(9, 262144);
  gemm_bf16_k<1, 0><<<dim3(8, 32), dim3(256), 0, stream>>>(xfb, mw(9), 1024, 1024, t1, nullptr, nullptr, nullptr, 0, nullptr);
  cvb(10, 524288);
  gemm_bf16_k<1, 0><<<dim3(16, 32), dim3(256), 0, stream>>>(t1, mw(10), 1024, 2048, t0, nullptr, nullptr, nullptr, 0, nullptr);
  cvb(11, 524288);
  gemm_bf16_k<0, 4><<<dim3(8, 32), dim3(256), 0, stream>>>(t0, mw(11), 2048, 1024, nullptr, nullptr, outp, wts, 3, moe);
}